// Round 8
// baseline (505.433 us; speedup 1.0000x reference)
//
#include <hip/hip_runtime.h>
#include <cstdint>
#include <cstddef>

typedef __attribute__((ext_vector_type(8))) short short8;
typedef __attribute__((ext_vector_type(4))) float f32x4;
typedef unsigned short u16;
typedef unsigned int u32;

__device__ __forceinline__ u16 bf16rne(float v)
{
    union { float f; u32 u; } a; a.f = v;
    return (u16)((a.u + 0x7fffu + ((a.u >> 16) & 1u)) >> 16);
}

__device__ __forceinline__ float bf16f(u16 h)
{
    union { u32 u; float f; } b; b.u = ((u32)h) << 16;
    return b.f;
}

// async global->LDS, 16B per lane. LDS dest is wave-uniform base + lane*16.
__device__ __forceinline__ void gload16(const u16* g, u16* l)
{
    __builtin_amdgcn_global_load_lds(
        (const __attribute__((address_space(1))) u32*)g,
        (__attribute__((address_space(3))) u32*)l, 16, 0, 0);
}

// ---------------------------------------------------------------------------
// bf16 MFMA GEMM, 2-phase prefetch: C = act(A @ Bt^T + bias).
// A[M,K] bf16, Bt[N,K] bf16 (pre-transposed). BM=128, BN=128, BK=64;
// 4 waves 2x2, wave tile 64x64 (4x4 frags of 16x16x32).
// Double-buffered LDS (64KB): issue global_load_lds for tile t+1, THEN
// ds_read+MFMA tile t, THEN one barrier (its vmcnt(0) drain lands after
// compute has covered the load latency). XOR-swizzle on the global source
// (linear LDS dest) + same XOR on ds_read -> conflict-free (involution).
// A rows may over-read past M (buffers padded); B cols past N (weights
// padded); stores guarded. act: 0=none 1=ELU 2=sigmoid. K%64==0.
// ---------------------------------------------------------------------------
#define BM 128
#define BN 128
#define BK 64

__global__ __launch_bounds__(256)
void gemm_mfma(const u16* __restrict__ A, const u16* __restrict__ Bt,
               const float* __restrict__ bias,
               float* __restrict__ Cf, u16* __restrict__ Cp,
               int M, int N, int K, int act)
{
    __shared__ __align__(16) u16 sA[2][BM * BK];   // 2 x 16 KB
    __shared__ __align__(16) u16 sB[2][BN * BK];   // 2 x 16 KB
    const int t = threadIdx.x;
    const int w = t >> 6, lane = t & 63;
    const int lr = lane & 15, lg = lane >> 4;
    const int row0 = blockIdx.y * BM, col0 = blockIdx.x * BN;
    const int wr = (w & 1) * 64, wc = (w >> 1) * 64;
    const int srow = lane >> 3, slot = lane & 7;   // staging coords in 1KB chunk

    f32x4 acc[4][4];
    #pragma unroll
    for (int m = 0; m < 4; ++m)
        #pragma unroll
        for (int n = 0; n < 4; ++n) acc[m][n] = (f32x4)0.f;

    const int nt = K / BK;

    // prologue: stage tile 0 into buffer 0
    {
        #pragma unroll
        for (int i = 0; i < 4; ++i) {
            int ci = w * 4 + i;
            int row = ci * 8 + srow;
            gload16(A + (size_t)(row0 + row) * K + ((slot ^ (row & 7)) << 3), &sA[0][ci * 512]);
        }
        #pragma unroll
        for (int i = 0; i < 4; ++i) {
            int ci = w * 4 + i;
            int col = ci * 8 + srow;
            gload16(Bt + (size_t)(col0 + col) * K + ((slot ^ (col & 7)) << 3), &sB[0][ci * 512]);
        }
    }
    __syncthreads();

    for (int kt = 0; kt < nt; ++kt) {
        // issue prefetch of tile kt+1 (async; drained by the barrier below,
        // after compute has covered the latency)
        if (kt + 1 < nt) {
            int nb = (kt + 1) & 1;
            int k0 = (kt + 1) * BK;
            #pragma unroll
            for (int i = 0; i < 4; ++i) {
                int ci = w * 4 + i;
                int row = ci * 8 + srow;
                gload16(A + (size_t)(row0 + row) * K + k0 + ((slot ^ (row & 7)) << 3), &sA[nb][ci * 512]);
            }
            #pragma unroll
            for (int i = 0; i < 4; ++i) {
                int ci = w * 4 + i;
                int col = ci * 8 + srow;
                gload16(Bt + (size_t)(col0 + col) * K + k0 + ((slot ^ (col & 7)) << 3), &sB[nb][ci * 512]);
            }
        }
        // compute tile kt from buffer kt&1
        const u16* pA = sA[kt & 1];
        const u16* pB = sB[kt & 1];
        #pragma unroll
        for (int kk = 0; kk < 2; ++kk) {
            short8 af[4], bfr[4];
            #pragma unroll
            for (int m = 0; m < 4; ++m) {
                int row = wr + m * 16 + lr;
                af[m] = *(const short8*)&pA[row * 64 + (((kk * 4 + lg) ^ (lr & 7)) << 3)];
            }
            #pragma unroll
            for (int n = 0; n < 4; ++n) {
                int col = wc + n * 16 + lr;
                bfr[n] = *(const short8*)&pB[col * 64 + (((kk * 4 + lg) ^ (lr & 7)) << 3)];
            }
            #pragma unroll
            for (int m = 0; m < 4; ++m)
                #pragma unroll
                for (int n = 0; n < 4; ++n)
                    acc[m][n] = __builtin_amdgcn_mfma_f32_16x16x32_bf16(af[m], bfr[n], acc[m][n], 0, 0, 0);
        }
        __syncthreads();
    }

    // epilogue: C/D frag col=lane&15, row=(lane>>4)*4+reg
    #pragma unroll
    for (int m = 0; m < 4; ++m) {
        int grow = row0 + wr + m * 16 + lg * 4;
        #pragma unroll
        for (int n = 0; n < 4; ++n) {
            int gcol = col0 + wc + n * 16 + lr;
            if (gcol >= N) continue;
            float bv = bias ? bias[gcol] : 0.f;
            #pragma unroll
            for (int q = 0; q < 4; ++q) {
                int r = grow + q;
                if (r >= M) continue;
                float v = acc[m][n][q] + bv;
                if (act == 1)      v = v > 0.f ? v : expm1f(v);
                else if (act == 2) v = 1.f / (1.f + expf(-v));
                size_t o = (size_t)r * N + gcol;
                if (Cf) Cf[o] = v;
                else Cp[o] = bf16rne(v);
            }
        }
    }
}

// ---------------------------------------------------------------------------
// weight prep (fp32 [K,N] -> transposed bf16 [N,K])
// ---------------------------------------------------------------------------
__global__ __launch_bounds__(256)
void wsplit_conv(const float* __restrict__ Wl1, const float* __restrict__ Wr1,
                 const float* __restrict__ Wl2, const float* __restrict__ Wr2,
                 u16* __restrict__ T1, u16* __restrict__ T2)
{
    int idx = blockIdx.x * 256 + threadIdx.x;   // 0..16383
    int z = blockIdx.y;                          // 0..3
    int k = idx >> 7, n = idx & 127;
    const float* W = (z == 0) ? Wl1 : (z == 1) ? Wr1 : (z == 2) ? Wl2 : Wr2;
    u16* T = (z < 2) ? T1 : T2;
    int half = z & 1;
    T[(size_t)(n + half * 128) * 128 + k] = bf16rne(W[(size_t)k * 128 + n]);
}

// all three MLP weights in one dispatch (flattened element index)
__global__ __launch_bounds__(256)
void wsplit_mlp(const float* __restrict__ W1, const float* __restrict__ W2,
                const float* __restrict__ W3,
                u16* __restrict__ T1, u16* __restrict__ T2, u16* __restrict__ T3)
{
    int i = blockIdx.x * 256 + threadIdx.x;
    const int n1 = 128 * 640, n2 = 640 * 320, n3 = 320 * 64;
    if (i < n1) {
        int k = i / 640, n = i % 640;
        T1[(size_t)n * 128 + k] = bf16rne(W1[i]);
    } else if (i < n1 + n2) {
        int j = i - n1;
        int k = j / 320, n = j % 320;
        T2[(size_t)n * 640 + k] = bf16rne(W2[j]);
    } else if (i < n1 + n2 + n3) {
        int j = i - n1 - n2;
        int k = j / 64, n = j % 64;
        T3[(size_t)n * 320 + k] = bf16rne(W3[j]);
    }
}

__global__ __launch_bounds__(256)
void xsplit_kernel(const float* __restrict__ x, u16* __restrict__ xh, int total)
{
    int i = blockIdx.x * 256 + threadIdx.x;
    if (i >= total) return;
    xh[i] = bf16rne(x[i]);
}

// ---------------------------------------------------------------------------
// CSR build
// ---------------------------------------------------------------------------
__global__ __launch_bounds__(256)
void histo_kernel(const int* __restrict__ ei, int E, int Etot, int* __restrict__ deg)
{
    int e = blockIdx.x * 256 + threadIdx.x;
    if (e >= Etot) return;
    int dst = (e < E) ? ei[E + e] : (e - E);
    atomicAdd(&deg[dst], 1);
}

__global__ __launch_bounds__(256)
void scan1_kernel(const int* __restrict__ deg, int* __restrict__ off,
                  int* __restrict__ bsum, int N)
{
    __shared__ int sh[256];
    int base = blockIdx.x * 1024;
    int t = threadIdx.x;
    int v[4]; int s = 0;
    #pragma unroll
    for (int i = 0; i < 4; ++i) {
        int idx = base + t * 4 + i;
        v[i] = (idx < N) ? deg[idx] : 0;
        s += v[i];
    }
    sh[t] = s;
    __syncthreads();
    for (int d = 1; d < 256; d <<= 1) {
        int x = 0;
        if (t >= d) x = sh[t - d];
        __syncthreads();
        if (t >= d) sh[t] += x;
        __syncthreads();
    }
    int excl = (t > 0) ? sh[t - 1] : 0;
    #pragma unroll
    for (int i = 0; i < 4; ++i) {
        int idx = base + t * 4 + i;
        if (idx < N) off[idx] = excl;
        excl += v[i];
    }
    if (t == 255) bsum[blockIdx.x] = sh[255];
}

__global__ void scan2_kernel(int* __restrict__ bsum, int nb, int* __restrict__ off_last)
{
    if (threadIdx.x == 0) {
        int run = 0;
        for (int i = 0; i < nb; ++i) { int v = bsum[i]; bsum[i] = run; run += v; }
        *off_last = run;
    }
}

__global__ __launch_bounds__(256)
void scan3_kernel(int* __restrict__ off, const int* __restrict__ bsum, int N)
{
    int i = blockIdx.x * 256 + threadIdx.x;
    if (i < N) off[i] += bsum[i >> 10];
}

__global__ __launch_bounds__(256)
void scatter_kernel(const int* __restrict__ ei, int E, int Etot,
                    const int* __restrict__ off, int* __restrict__ cnt,
                    int* __restrict__ csrc)
{
    int e = blockIdx.x * 256 + threadIdx.x;
    if (e >= Etot) return;
    int src, dst;
    if (e < E) { src = ei[e]; dst = ei[E + e]; }
    else       { src = dst = e - E; }
    int pos = off[dst] + atomicAdd(&cnt[dst], 1);
    csrc[pos] = src;
}

// ---------------------------------------------------------------------------
// Fused GATv2 edge pass (VALU-bound at ~80%; at op floor — unchanged).
// ---------------------------------------------------------------------------
__global__ __launch_bounds__(256)
void gat_fused(const u16* __restrict__ xlxr,
               const int* __restrict__ off, const int* __restrict__ csrc,
               const float* __restrict__ att, const float* __restrict__ bias,
               u16* __restrict__ outp, int N)
{
    const int wave = threadIdx.x >> 6;
    const int lane = threadIdx.x & 63;
    const int node = blockIdx.x * 4 + wave;
    if (node >= N) return;
    const int c = lane * 2;

    const float a0 = att[c];
    const float a1 = att[c + 1];
    u32 xrw = *(const u32*)(xlxr + (size_t)node * 256 + 128 + c);
    const float xr0 = bf16f((u16)xrw);
    const float xr1 = bf16f((u16)(xrw >> 16));

    float acc0 = 0.f, acc1 = 0.f, s = 0.f;
    const int beg = off[node];
    const int end = off[node + 1];

    int e = beg;
    for (; e + 4 <= end; e += 4) {
        int s0 = csrc[e], s1 = csrc[e + 1], s2 = csrc[e + 2], s3 = csrc[e + 3];
        u32 wa = *(const u32*)(xlxr + (size_t)s0 * 256 + c);
        u32 wb = *(const u32*)(xlxr + (size_t)s1 * 256 + c);
        u32 wc = *(const u32*)(xlxr + (size_t)s2 * 256 + c);
        u32 wd = *(const u32*)(xlxr + (size_t)s3 * 256 + c);
        float xa0 = bf16f((u16)wa), xa1 = bf16f((u16)(wa >> 16));
        float xb0 = bf16f((u16)wb), xb1 = bf16f((u16)(wb >> 16));
        float xc0 = bf16f((u16)wc), xc1 = bf16f((u16)(wc >> 16));
        float xd0 = bf16f((u16)wd), xd1 = bf16f((u16)(wd >> 16));
        float t0, t1;
        t0 = xa0 + xr0; t0 = t0 > 0.f ? t0 : 0.2f * t0;
        t1 = xa1 + xr1; t1 = t1 > 0.f ? t1 : 0.2f * t1;
        float za = fmaf(t0, a0, t1 * a1);
        t0 = xb0 + xr0; t0 = t0 > 0.f ? t0 : 0.2f * t0;
        t1 = xb1 + xr1; t1 = t1 > 0.f ? t1 : 0.2f * t1;
        float zb = fmaf(t0, a0, t1 * a1);
        t0 = xc0 + xr0; t0 = t0 > 0.f ? t0 : 0.2f * t0;
        t1 = xc1 + xr1; t1 = t1 > 0.f ? t1 : 0.2f * t1;
        float zc = fmaf(t0, a0, t1 * a1);
        t0 = xd0 + xr0; t0 = t0 > 0.f ? t0 : 0.2f * t0;
        t1 = xd1 + xr1; t1 = t1 > 0.f ? t1 : 0.2f * t1;
        float zd = fmaf(t0, a0, t1 * a1);
        #pragma unroll
        for (int m = 1; m < 16; m <<= 1) {
            za += __shfl_xor(za, m, 64);
            zb += __shfl_xor(zb, m, 64);
            zc += __shfl_xor(zc, m, 64);
            zd += __shfl_xor(zd, m, 64);
        }
        float pa = __expf(za), pb = __expf(zb), pc = __expf(zc), pd = __expf(zd);
        s += (pa + pb) + (pc + pd);
        acc0 = fmaf(pa, xa0, fmaf(pb, xb0, fmaf(pc, xc0, fmaf(pd, xd0, acc0))));
        acc1 = fmaf(pa, xa1, fmaf(pb, xb1, fmaf(pc, xc1, fmaf(pd, xd1, acc1))));
    }
    for (; e < end; ++e) {
        int src = csrc[e];
        u32 xw = *(const u32*)(xlxr + (size_t)src * 256 + c);
        float x0 = bf16f((u16)xw);
        float x1 = bf16f((u16)(xw >> 16));
        float z0 = x0 + xr0; z0 = z0 > 0.f ? z0 : 0.2f * z0;
        float z1 = x1 + xr1; z1 = z1 > 0.f ? z1 : 0.2f * z1;
        float z = fmaf(z0, a0, z1 * a1);
        #pragma unroll
        for (int m = 1; m < 16; m <<= 1)
            z += __shfl_xor(z, m, 64);
        float p = __expf(z);
        s += p;
        acc0 = fmaf(p, x0, acc0);
        acc1 = fmaf(p, x1, acc1);
    }

    float inv = 1.f / s;
    float v0 = acc0 * inv + bias[c];
    float v1 = acc1 * inv + bias[c + 1];
    v0 = v0 > 0.f ? v0 : expm1f(v0);
    v1 = v1 > 0.f ? v1 : expm1f(v1);
    *(u32*)(outp + (size_t)node * 128 + c) = (u32)bf16rne(v0) | ((u32)bf16rne(v1) << 16);
}

// ---------------------------------------------------------------------------
extern "C" void kernel_launch(void* const* d_in, const int* in_sizes, int n_in,
                              void* d_out, int out_size, void* d_ws, size_t ws_size,
                              hipStream_t stream)
{
    const float* x    = (const float*)d_in[0];
    const int*   ei   = (const int*)  d_in[1];
    const float* Wl1  = (const float*)d_in[2];
    const float* Wr1  = (const float*)d_in[3];
    const float* att1 = (const float*)d_in[4];
    const float* b1   = (const float*)d_in[5];
    const float* Wl2  = (const float*)d_in[6];
    const float* Wr2  = (const float*)d_in[7];
    const float* att2 = (const float*)d_in[8];
    const float* b2   = (const float*)d_in[9];
    const float* W1   = (const float*)d_in[10];
    const float* bb1  = (const float*)d_in[11];
    const float* W2   = (const float*)d_in[12];
    const float* bb2  = (const float*)d_in[13];
    const float* W3   = (const float*)d_in[14];
    const float* bb3  = (const float*)d_in[15];
    float* out = (float*)d_out;

    const int Nn   = in_sizes[0] / 128;
    const int E    = in_sizes[1] / 2;
    const int Etot = E + Nn;
    const int PAD  = 128;   // A-side row padding for unguarded gload_lds

    char* base = (char*)d_ws;
    size_t woff = 0;
    auto alloc = [&](size_t bytes) -> void* {
        woff = (woff + 255) & ~(size_t)255;
        void* p = base + woff;
        woff += bytes;
        return p;
    };
    u16* xh   = (u16*)alloc((size_t)(Nn + PAD) * 128 * 2);
    u16* xlxr = (u16*)alloc((size_t)Nn * 256 * 2);
    u16* h1   = (u16*)alloc((size_t)(Nn + PAD) * 128 * 2);
    u16* h2   = (u16*)alloc((size_t)(Nn + PAD) * 128 * 2);
    u16* WLR1 = (u16*)alloc((size_t)256 * 128 * 2);
    u16* WLR2 = (u16*)alloc((size_t)256 * 128 * 2);
    u16* W1t  = (u16*)alloc((size_t)640 * 128 * 2);
    u16* W2t  = (u16*)alloc((size_t)384 * 640 * 2);   // N=320 padded to 384
    u16* W3t  = (u16*)alloc((size_t)128 * 320 * 2);   // N=64 padded to 128
    int* off  = (int*)alloc((size_t)(Nn + 1) * 4);
    int* bsum = (int*)alloc(64 * 4);
    int* deg  = (int*)alloc((size_t)Nn * 4);
    int* csrc = (int*)alloc((size_t)Etot * 4);

    dim3 blk(256);
    auto gemm = [&](const u16* A, const u16* Bt, const float* bias,
                    float* Cf, u16* Cp, int M, int N, int K, int act) {
        dim3 grid((N + BN - 1) / BN, (M + BM - 1) / BM);
        hipLaunchKernelGGL(gemm_mfma, grid, blk, 0, stream, A, Bt, bias, Cf, Cp, M, N, K, act);
    };

    const int eb  = (Etot + 255) / 256;
    const int nb  = (Nn + 1023) / 1024;
    const int nb2 = (Nn + 255) / 256;
    const int gatb = (Nn + 3) / 4;

    // ---- CSR build (once) ----
    hipMemsetAsync(deg, 0, (size_t)Nn * sizeof(int), stream);
    hipLaunchKernelGGL(histo_kernel, dim3(eb), blk, 0, stream, ei, E, Etot, deg);
    hipLaunchKernelGGL(scan1_kernel, dim3(nb), blk, 0, stream, deg, off, bsum, Nn);
    hipLaunchKernelGGL(scan2_kernel, dim3(1), dim3(64), 0, stream, bsum, nb, off + Nn);
    hipLaunchKernelGGL(scan3_kernel, dim3(nb2), blk, 0, stream, off, bsum, Nn);
    hipMemsetAsync(deg, 0, (size_t)Nn * sizeof(int), stream);
    hipLaunchKernelGGL(scatter_kernel, dim3(eb), blk, 0, stream, ei, E, Etot, off, deg, csrc);

    // ---- prep: bf16 convert + transposed weights ----
    hipLaunchKernelGGL(xsplit_kernel, dim3((Nn * 128 + 255) / 256), blk, 0, stream, x, xh, Nn * 128);
    hipLaunchKernelGGL(wsplit_conv, dim3(64, 4), blk, 0, stream, Wl1, Wr1, Wl2, Wr2, WLR1, WLR2);
    const int wtot = 128 * 640 + 640 * 320 + 320 * 64;
    hipLaunchKernelGGL(wsplit_mlp, dim3((wtot + 255) / 256), blk, 0, stream,
                       W1, W2, W3, W1t, W2t, W3t);

    // ---- conv1 ----
    gemm(xh, WLR1, nullptr, nullptr, xlxr, Nn, 256, 128, 0);
    hipLaunchKernelGGL(gat_fused, dim3(gatb), blk, 0, stream, xlxr, off, csrc, att1, b1, h1, Nn);

    // ---- conv2 ----
    gemm(h1, WLR2, nullptr, nullptr, xlxr, Nn, 256, 128, 0);
    hipLaunchKernelGGL(gat_fused, dim3(gatb), blk, 0, stream, xlxr, off, csrc, att2, b2, h2, Nn);

    // ---- MLP head: full-M if workspace allows, else chunked overlay ----
    size_t need = ((size_t)(Nn + PAD) * 640 + (size_t)(Nn + PAD) * 320) * 2 + 512;
    int CHUNK;
    u16 *t1, *t2;
    if (ws_size - woff >= need) {
        CHUNK = Nn;
        t1 = (u16*)alloc((size_t)(Nn + PAD) * 640 * 2);
        t2 = (u16*)alloc((size_t)(Nn + PAD) * 320 * 2);
    } else {
        CHUNK = 25000;                       // overlay dead front region (51.2 MB)
        t1 = (u16*)base;                     // 25128*640*2 = 32.2 MB
        t2 = t1 + (size_t)(CHUNK + PAD) * 640;   // 16.1 MB, total 48.3 < 51.2
    }
    for (int c0 = 0; c0 < Nn; c0 += CHUNK) {
        int cm = (Nn - c0) < CHUNK ? (Nn - c0) : CHUNK;
        gemm(h2 + (size_t)c0 * 128, W1t, bb1, nullptr, t1, cm, 640, 128, 1);
        gemm(t1, W2t, bb2, nullptr, t2, cm, 320, 640, 1);
        gemm(t2, W3t, bb3, out + (size_t)c0 * 64, nullptr, cm, 64, 320, 2);
    }
}

// Round 9
// 449.510 us; speedup vs baseline: 1.1244x; 1.1244x over previous
//
#include <hip/hip_runtime.h>
#include <cstdint>
#include <cstddef>

typedef __attribute__((ext_vector_type(8))) short short8;
typedef __attribute__((ext_vector_type(4))) float f32x4;
typedef unsigned short u16;
typedef unsigned int u32;

__device__ __forceinline__ u16 bf16rne(float v)
{
    union { float f; u32 u; } a; a.f = v;
    return (u16)((a.u + 0x7fffu + ((a.u >> 16) & 1u)) >> 16);
}

__device__ __forceinline__ float bf16f(u16 h)
{
    union { u32 u; float f; } b; b.u = ((u32)h) << 16;
    return b.f;
}

// async global->LDS, 16B per lane. LDS dest is wave-uniform base + lane*16.
__device__ __forceinline__ void gload16(const u16* g, u16* l)
{
    __builtin_amdgcn_global_load_lds(
        (const __attribute__((address_space(1))) u32*)g,
        (__attribute__((address_space(3))) u32*)l, 16, 0, 0);
}

// ---------------------------------------------------------------------------
// bf16 MFMA GEMM: C = act(A @ Bt^T + bias). A[M,K] bf16, Bt[N,K] bf16.
// BM=128, BN=128, BK=64; 4 waves 2x2, wave tile 64x64 (4x4 frags of
// 16x16x32) -> 16 ds_read_b128 : 32 MFMA per wave per K-tile.
// Single-buffered LDS (32KB -> ~5 blocks/CU; R8 showed dbuf's 64KB
// occupancy hit outweighs prefetch). Staging via global_load_lds with
// inverse-XOR-swizzled global source + same XOR on ds_read (involution).
// XCD-chunk bijective blockIdx swizzle (m204): consecutive x-major tiles
// land on the same XCD's L2 so column-siblings re-read the A-panel from
// L2 (~200cy) instead of HBM (~900cy).
// A rows may over-read past M (buffers padded); B cols past N (weights
// padded); stores guarded. act: 0=none 1=ELU 2=sigmoid. K%64==0.
// ---------------------------------------------------------------------------
#define BM 128
#define BN 128
#define BK 64

__global__ __launch_bounds__(256)
void gemm_mfma(const u16* __restrict__ A, const u16* __restrict__ Bt,
               const float* __restrict__ bias,
               float* __restrict__ Cf, u16* __restrict__ Cp,
               int M, int N, int K, int act)
{
    __shared__ __align__(16) u16 sA[BM * BK];   // 16 KB
    __shared__ __align__(16) u16 sB[BN * BK];   // 16 KB
    const int t = threadIdx.x;
    const int w = t >> 6, lane = t & 63;
    const int lr = lane & 15, lg = lane >> 4;

    // bijective XCD-chunk swizzle (8 XCDs)
    const int nwg = gridDim.x * gridDim.y;
    int orig = blockIdx.y * gridDim.x + blockIdx.x;
    int q = nwg >> 3, r = nwg & 7;
    int xcd = orig & 7, slotid = orig >> 3;
    int wgid = (xcd < r ? xcd * (q + 1) : r * (q + 1) + (xcd - r) * q) + slotid;
    int bx = wgid % gridDim.x;
    int by = wgid / gridDim.x;

    const int row0 = by * BM, col0 = bx * BN;
    const int wr = (w & 1) * 64, wc = (w >> 1) * 64;
    const int srow = lane >> 3, slot = lane & 7;   // staging coords in 1KB chunk

    f32x4 acc[4][4];
    #pragma unroll
    for (int m = 0; m < 4; ++m)
        #pragma unroll
        for (int n = 0; n < 4; ++n) acc[m][n] = (f32x4)0.f;

    for (int k0 = 0; k0 < K; k0 += BK) {
        // stage A: 16 chunks of 1KB (8 rows x 128B); wave w takes chunks w*4+i.
        // LDS slot (row, s) receives global k-chunk (s ^ (row&7)).
        #pragma unroll
        for (int i = 0; i < 4; ++i) {
            int ci = w * 4 + i;
            int row = ci * 8 + srow;
            const u16* g = A + (size_t)(row0 + row) * K + k0 + ((slot ^ (row & 7)) << 3);
            gload16(g, &sA[ci * 512]);
        }
        // stage B: 16 chunks (8 cols each)
        #pragma unroll
        for (int i = 0; i < 4; ++i) {
            int ci = w * 4 + i;
            int col = ci * 8 + srow;
            const u16* g = Bt + (size_t)(col0 + col) * K + k0 + ((slot ^ (col & 7)) << 3);
            gload16(g, &sB[ci * 512]);
        }
        __syncthreads();   // drains vmcnt (gload_lds) for all waves
        #pragma unroll
        for (int kk = 0; kk < 2; ++kk) {
            short8 af[4], bfr[4];
            #pragma unroll
            for (int m = 0; m < 4; ++m) {
                int row = wr + m * 16 + lr;
                af[m] = *(const short8*)&sA[row * 64 + (((kk * 4 + lg) ^ (lr & 7)) << 3)];
            }
            #pragma unroll
            for (int n = 0; n < 4; ++n) {
                int col = wc + n * 16 + lr;
                bfr[n] = *(const short8*)&sB[col * 64 + (((kk * 4 + lg) ^ (lr & 7)) << 3)];
            }
            #pragma unroll
            for (int m = 0; m < 4; ++m)
                #pragma unroll
                for (int n = 0; n < 4; ++n)
                    acc[m][n] = __builtin_amdgcn_mfma_f32_16x16x32_bf16(af[m], bfr[n], acc[m][n], 0, 0, 0);
        }
        __syncthreads();
    }

    // epilogue: C/D frag col=lane&15, row=(lane>>4)*4+reg
    #pragma unroll
    for (int m = 0; m < 4; ++m) {
        int grow = row0 + wr + m * 16 + lg * 4;
        #pragma unroll
        for (int n = 0; n < 4; ++n) {
            int gcol = col0 + wc + n * 16 + lr;
            if (gcol >= N) continue;
            float bv = bias ? bias[gcol] : 0.f;
            #pragma unroll
            for (int q2 = 0; q2 < 4; ++q2) {
                int rr = grow + q2;
                if (rr >= M) continue;
                float v = acc[m][n][q2] + bv;
                if (act == 1)      v = v > 0.f ? v : expm1f(v);
                else if (act == 2) v = 1.f / (1.f + expf(-v));
                size_t o = (size_t)rr * N + gcol;
                if (Cf) Cf[o] = v;
                else Cp[o] = bf16rne(v);
            }
        }
    }
}

// ---------------------------------------------------------------------------
// weight prep (fp32 [K,N] -> transposed bf16 [N,K])
// ---------------------------------------------------------------------------
__global__ __launch_bounds__(256)
void wsplit_conv(const float* __restrict__ Wl1, const float* __restrict__ Wr1,
                 const float* __restrict__ Wl2, const float* __restrict__ Wr2,
                 u16* __restrict__ T1, u16* __restrict__ T2)
{
    int idx = blockIdx.x * 256 + threadIdx.x;   // 0..16383
    int z = blockIdx.y;                          // 0..3
    int k = idx >> 7, n = idx & 127;
    const float* W = (z == 0) ? Wl1 : (z == 1) ? Wr1 : (z == 2) ? Wl2 : Wr2;
    u16* T = (z < 2) ? T1 : T2;
    int half = z & 1;
    T[(size_t)(n + half * 128) * 128 + k] = bf16rne(W[(size_t)k * 128 + n]);
}

// all three MLP weights in one dispatch (flattened element index)
__global__ __launch_bounds__(256)
void wsplit_mlp(const float* __restrict__ W1, const float* __restrict__ W2,
                const float* __restrict__ W3,
                u16* __restrict__ T1, u16* __restrict__ T2, u16* __restrict__ T3)
{
    int i = blockIdx.x * 256 + threadIdx.x;
    const int n1 = 128 * 640, n2 = 640 * 320, n3 = 320 * 64;
    if (i < n1) {
        int k = i / 640, n = i % 640;
        T1[(size_t)n * 128 + k] = bf16rne(W1[i]);
    } else if (i < n1 + n2) {
        int j = i - n1;
        int k = j / 320, n = j % 320;
        T2[(size_t)n * 640 + k] = bf16rne(W2[j]);
    } else if (i < n1 + n2 + n3) {
        int j = i - n1 - n2;
        int k = j / 64, n = j % 64;
        T3[(size_t)n * 320 + k] = bf16rne(W3[j]);
    }
}

__global__ __launch_bounds__(256)
void xsplit_kernel(const float* __restrict__ x, u16* __restrict__ xh, int total)
{
    int i = blockIdx.x * 256 + threadIdx.x;
    if (i >= total) return;
    xh[i] = bf16rne(x[i]);
}

// ---------------------------------------------------------------------------
// CSR build
// ---------------------------------------------------------------------------
__global__ __launch_bounds__(256)
void histo_kernel(const int* __restrict__ ei, int E, int Etot, int* __restrict__ deg)
{
    int e = blockIdx.x * 256 + threadIdx.x;
    if (e >= Etot) return;
    int dst = (e < E) ? ei[E + e] : (e - E);
    atomicAdd(&deg[dst], 1);
}

__global__ __launch_bounds__(256)
void scan1_kernel(const int* __restrict__ deg, int* __restrict__ off,
                  int* __restrict__ bsum, int N)
{
    __shared__ int sh[256];
    int base = blockIdx.x * 1024;
    int t = threadIdx.x;
    int v[4]; int s = 0;
    #pragma unroll
    for (int i = 0; i < 4; ++i) {
        int idx = base + t * 4 + i;
        v[i] = (idx < N) ? deg[idx] : 0;
        s += v[i];
    }
    sh[t] = s;
    __syncthreads();
    for (int d = 1; d < 256; d <<= 1) {
        int x = 0;
        if (t >= d) x = sh[t - d];
        __syncthreads();
        if (t >= d) sh[t] += x;
        __syncthreads();
    }
    int excl = (t > 0) ? sh[t - 1] : 0;
    #pragma unroll
    for (int i = 0; i < 4; ++i) {
        int idx = base + t * 4 + i;
        if (idx < N) off[idx] = excl;
        excl += v[i];
    }
    if (t == 255) bsum[blockIdx.x] = sh[255];
}

__global__ void scan2_kernel(int* __restrict__ bsum, int nb, int* __restrict__ off_last)
{
    if (threadIdx.x == 0) {
        int run = 0;
        for (int i = 0; i < nb; ++i) { int v = bsum[i]; bsum[i] = run; run += v; }
        *off_last = run;
    }
}

__global__ __launch_bounds__(256)
void scan3_kernel(int* __restrict__ off, const int* __restrict__ bsum, int N)
{
    int i = blockIdx.x * 256 + threadIdx.x;
    if (i < N) off[i] += bsum[i >> 10];
}

__global__ __launch_bounds__(256)
void scatter_kernel(const int* __restrict__ ei, int E, int Etot,
                    const int* __restrict__ off, int* __restrict__ cnt,
                    int* __restrict__ csrc)
{
    int e = blockIdx.x * 256 + threadIdx.x;
    if (e >= Etot) return;
    int src, dst;
    if (e < E) { src = ei[e]; dst = ei[E + e]; }
    else       { src = dst = e - E; }
    int pos = off[dst] + atomicAdd(&cnt[dst], 1);
    csrc[pos] = src;
}

// ---------------------------------------------------------------------------
// Fused GATv2 edge pass (VALU-bound at ~80%; at op floor — unchanged).
// ---------------------------------------------------------------------------
__global__ __launch_bounds__(256)
void gat_fused(const u16* __restrict__ xlxr,
               const int* __restrict__ off, const int* __restrict__ csrc,
               const float* __restrict__ att, const float* __restrict__ bias,
               u16* __restrict__ outp, int N)
{
    const int wave = threadIdx.x >> 6;
    const int lane = threadIdx.x & 63;
    const int node = blockIdx.x * 4 + wave;
    if (node >= N) return;
    const int c = lane * 2;

    const float a0 = att[c];
    const float a1 = att[c + 1];
    u32 xrw = *(const u32*)(xlxr + (size_t)node * 256 + 128 + c);
    const float xr0 = bf16f((u16)xrw);
    const float xr1 = bf16f((u16)(xrw >> 16));

    float acc0 = 0.f, acc1 = 0.f, s = 0.f;
    const int beg = off[node];
    const int end = off[node + 1];

    int e = beg;
    for (; e + 4 <= end; e += 4) {
        int s0 = csrc[e], s1 = csrc[e + 1], s2 = csrc[e + 2], s3 = csrc[e + 3];
        u32 wa = *(const u32*)(xlxr + (size_t)s0 * 256 + c);
        u32 wb = *(const u32*)(xlxr + (size_t)s1 * 256 + c);
        u32 wc = *(const u32*)(xlxr + (size_t)s2 * 256 + c);
        u32 wd = *(const u32*)(xlxr + (size_t)s3 * 256 + c);
        float xa0 = bf16f((u16)wa), xa1 = bf16f((u16)(wa >> 16));
        float xb0 = bf16f((u16)wb), xb1 = bf16f((u16)(wb >> 16));
        float xc0 = bf16f((u16)wc), xc1 = bf16f((u16)(wc >> 16));
        float xd0 = bf16f((u16)wd), xd1 = bf16f((u16)(wd >> 16));
        float t0, t1;
        t0 = xa0 + xr0; t0 = t0 > 0.f ? t0 : 0.2f * t0;
        t1 = xa1 + xr1; t1 = t1 > 0.f ? t1 : 0.2f * t1;
        float za = fmaf(t0, a0, t1 * a1);
        t0 = xb0 + xr0; t0 = t0 > 0.f ? t0 : 0.2f * t0;
        t1 = xb1 + xr1; t1 = t1 > 0.f ? t1 : 0.2f * t1;
        float zb = fmaf(t0, a0, t1 * a1);
        t0 = xc0 + xr0; t0 = t0 > 0.f ? t0 : 0.2f * t0;
        t1 = xc1 + xr1; t1 = t1 > 0.f ? t1 : 0.2f * t1;
        float zc = fmaf(t0, a0, t1 * a1);
        t0 = xd0 + xr0; t0 = t0 > 0.f ? t0 : 0.2f * t0;
        t1 = xd1 + xr1; t1 = t1 > 0.f ? t1 : 0.2f * t1;
        float zd = fmaf(t0, a0, t1 * a1);
        #pragma unroll
        for (int m = 1; m < 16; m <<= 1) {
            za += __shfl_xor(za, m, 64);
            zb += __shfl_xor(zb, m, 64);
            zc += __shfl_xor(zc, m, 64);
            zd += __shfl_xor(zd, m, 64);
        }
        float pa = __expf(za), pb = __expf(zb), pc = __expf(zc), pd = __expf(zd);
        s += (pa + pb) + (pc + pd);
        acc0 = fmaf(pa, xa0, fmaf(pb, xb0, fmaf(pc, xc0, fmaf(pd, xd0, acc0))));
        acc1 = fmaf(pa, xa1, fmaf(pb, xb1, fmaf(pc, xc1, fmaf(pd, xd1, acc1))));
    }
    for (; e < end; ++e) {
        int src = csrc[e];
        u32 xw = *(const u32*)(xlxr + (size_t)src * 256 + c);
        float x0 = bf16f((u16)xw);
        float x1 = bf16f((u16)(xw >> 16));
        float z0 = x0 + xr0; z0 = z0 > 0.f ? z0 : 0.2f * z0;
        float z1 = x1 + xr1; z1 = z1 > 0.f ? z1 : 0.2f * z1;
        float z = fmaf(z0, a0, z1 * a1);
        #pragma unroll
        for (int m = 1; m < 16; m <<= 1)
            z += __shfl_xor(z, m, 64);
        float p = __expf(z);
        s += p;
        acc0 = fmaf(p, x0, acc0);
        acc1 = fmaf(p, x1, acc1);
    }

    float inv = 1.f / s;
    float v0 = acc0 * inv + bias[c];
    float v1 = acc1 * inv + bias[c + 1];
    v0 = v0 > 0.f ? v0 : expm1f(v0);
    v1 = v1 > 0.f ? v1 : expm1f(v1);
    *(u32*)(outp + (size_t)node * 128 + c) = (u32)bf16rne(v0) | ((u32)bf16rne(v1) << 16);
}

// ---------------------------------------------------------------------------
extern "C" void kernel_launch(void* const* d_in, const int* in_sizes, int n_in,
                              void* d_out, int out_size, void* d_ws, size_t ws_size,
                              hipStream_t stream)
{
    const float* x    = (const float*)d_in[0];
    const int*   ei   = (const int*)  d_in[1];
    const float* Wl1  = (const float*)d_in[2];
    const float* Wr1  = (const float*)d_in[3];
    const float* att1 = (const float*)d_in[4];
    const float* b1   = (const float*)d_in[5];
    const float* Wl2  = (const float*)d_in[6];
    const float* Wr2  = (const float*)d_in[7];
    const float* att2 = (const float*)d_in[8];
    const float* b2   = (const float*)d_in[9];
    const float* W1   = (const float*)d_in[10];
    const float* bb1  = (const float*)d_in[11];
    const float* W2   = (const float*)d_in[12];
    const float* bb2  = (const float*)d_in[13];
    const float* W3   = (const float*)d_in[14];
    const float* bb3  = (const float*)d_in[15];
    float* out = (float*)d_out;

    const int Nn   = in_sizes[0] / 128;
    const int E    = in_sizes[1] / 2;
    const int Etot = E + Nn;
    const int PAD  = 128;   // A-side row padding for unguarded gload_lds

    char* base = (char*)d_ws;
    size_t woff = 0;
    auto alloc = [&](size_t bytes) -> void* {
        woff = (woff + 255) & ~(size_t)255;
        void* p = base + woff;
        woff += bytes;
        return p;
    };
    u16* xh   = (u16*)alloc((size_t)(Nn + PAD) * 128 * 2);
    u16* xlxr = (u16*)alloc((size_t)Nn * 256 * 2);
    u16* h1   = (u16*)alloc((size_t)(Nn + PAD) * 128 * 2);
    u16* h2   = (u16*)alloc((size_t)(Nn + PAD) * 128 * 2);
    u16* WLR1 = (u16*)alloc((size_t)256 * 128 * 2);
    u16* WLR2 = (u16*)alloc((size_t)256 * 128 * 2);
    u16* W1t  = (u16*)alloc((size_t)640 * 128 * 2);
    u16* W2t  = (u16*)alloc((size_t)384 * 640 * 2);   // N=320 padded to 384
    u16* W3t  = (u16*)alloc((size_t)128 * 320 * 2);   // N=64 padded to 128
    int* off  = (int*)alloc((size_t)(Nn + 1) * 4);
    int* bsum = (int*)alloc(64 * 4);
    int* deg  = (int*)alloc((size_t)Nn * 4);
    int* csrc = (int*)alloc((size_t)Etot * 4);

    dim3 blk(256);
    auto gemm = [&](const u16* A, const u16* Bt, const float* bias,
                    float* Cf, u16* Cp, int M, int N, int K, int act) {
        dim3 grid((N + BN - 1) / BN, (M + BM - 1) / BM);
        hipLaunchKernelGGL(gemm_mfma, grid, blk, 0, stream, A, Bt, bias, Cf, Cp, M, N, K, act);
    };

    const int eb  = (Etot + 255) / 256;
    const int nb  = (Nn + 1023) / 1024;
    const int nb2 = (Nn + 255) / 256;
    const int gatb = (Nn + 3) / 4;

    // ---- CSR build (once) ----
    hipMemsetAsync(deg, 0, (size_t)Nn * sizeof(int), stream);
    hipLaunchKernelGGL(histo_kernel, dim3(eb), blk, 0, stream, ei, E, Etot, deg);
    hipLaunchKernelGGL(scan1_kernel, dim3(nb), blk, 0, stream, deg, off, bsum, Nn);
    hipLaunchKernelGGL(scan2_kernel, dim3(1), dim3(64), 0, stream, bsum, nb, off + Nn);
    hipLaunchKernelGGL(scan3_kernel, dim3(nb2), blk, 0, stream, off, bsum, Nn);
    hipMemsetAsync(deg, 0, (size_t)Nn * sizeof(int), stream);
    hipLaunchKernelGGL(scatter_kernel, dim3(eb), blk, 0, stream, ei, E, Etot, off, deg, csrc);

    // ---- prep: bf16 convert + transposed weights ----
    hipLaunchKernelGGL(xsplit_kernel, dim3((Nn * 128 + 255) / 256), blk, 0, stream, x, xh, Nn * 128);
    hipLaunchKernelGGL(wsplit_conv, dim3(64, 4), blk, 0, stream, Wl1, Wr1, Wl2, Wr2, WLR1, WLR2);
    const int wtot = 128 * 640 + 640 * 320 + 320 * 64;
    hipLaunchKernelGGL(wsplit_mlp, dim3((wtot + 255) / 256), blk, 0, stream,
                       W1, W2, W3, W1t, W2t, W3t);

    // ---- conv1 ----
    gemm(xh, WLR1, nullptr, nullptr, xlxr, Nn, 256, 128, 0);
    hipLaunchKernelGGL(gat_fused, dim3(gatb), blk, 0, stream, xlxr, off, csrc, att1, b1, h1, Nn);

    // ---- conv2 ----
    gemm(h1, WLR2, nullptr, nullptr, xlxr, Nn, 256, 128, 0);
    hipLaunchKernelGGL(gat_fused, dim3(gatb), blk, 0, stream, xlxr, off, csrc, att2, b2, h2, Nn);

    // ---- MLP head: full-M if workspace allows, else chunked overlay ----
    size_t need = ((size_t)(Nn + PAD) * 640 + (size_t)(Nn + PAD) * 320) * 2 + 512;
    int CHUNK;
    u16 *t1, *t2;
    if (ws_size - woff >= need) {
        CHUNK = Nn;
        t1 = (u16*)alloc((size_t)(Nn + PAD) * 640 * 2);
        t2 = (u16*)alloc((size_t)(Nn + PAD) * 320 * 2);
    } else {
        CHUNK = 25000;                       // overlay dead front region (51.2 MB)
        t1 = (u16*)base;                     // 25128*640*2 = 32.2 MB
        t2 = t1 + (size_t)(CHUNK + PAD) * 640;   // 16.1 MB, total 48.3 < 51.2
    }
    for (int c0 = 0; c0 < Nn; c0 += CHUNK) {
        int cm = (Nn - c0) < CHUNK ? (Nn - c0) : CHUNK;
        gemm(h2 + (size_t)c0 * 128, W1t, bb1, nullptr, t1, cm, 640, 128, 1);
        gemm(t1, W2t, bb2, nullptr, t2, cm, 320, 640, 1);
        gemm(t2, W3t, bb3, out + (size_t)c0 * 64, nullptr, cm, 64, 320, 2);
    }
}

// Round 10
// 418.714 us; speedup vs baseline: 1.2071x; 1.0735x over previous
//
#include <hip/hip_runtime.h>
#include <cstdint>
#include <cstddef>

typedef __attribute__((ext_vector_type(8))) short short8;
typedef __attribute__((ext_vector_type(4))) float f32x4;
typedef unsigned short u16;
typedef unsigned int u32;

__device__ __forceinline__ u16 bf16rne(float v)
{
    union { float f; u32 u; } a; a.f = v;
    return (u16)((a.u + 0x7fffu + ((a.u >> 16) & 1u)) >> 16);
}

__device__ __forceinline__ float bf16f(u16 h)
{
    union { u32 u; float f; } b; b.u = ((u32)h) << 16;
    return b.f;
}

// fast activations on the v_exp_f32 HW path (libm expm1f/expf are ~30-60
// instr sequences; these are 2-3). abs error ~1e-7 << bf16 quantum.
__device__ __forceinline__ float fast_elu(float v)
{
    return v > 0.f ? v : __expf(v) - 1.f;
}
__device__ __forceinline__ float fast_sigmoid(float v)
{
    return 1.f / (1.f + __expf(-v));
}

// async global->LDS, 16B per lane. LDS dest is wave-uniform base + lane*16.
__device__ __forceinline__ void gload16(const u16* g, u16* l)
{
    __builtin_amdgcn_global_load_lds(
        (const __attribute__((address_space(1))) u32*)g,
        (__attribute__((address_space(3))) u32*)l, 16, 0, 0);
}

// ---------------------------------------------------------------------------
// bf16 MFMA GEMM: C = act(A @ Bt^T + bias). A[M,K] bf16, Bt[N,K] bf16.
// BM=128, BN=128, BK=64; 4 waves 2x2, wave tile 64x64 (4x4 frags of
// 16x16x32). Single-buffered LDS (32KB; R8 showed dbuf's occupancy hit
// outweighs prefetch). global_load_lds staging with inverse-XOR-swizzled
// global source + same XOR on ds_read (involution). Bijective XCD-chunk
// blockIdx swizzle for L2 locality of shared panels.
// A rows may over-read past M (buffers padded); B cols past N (weights
// padded); stores guarded. act: 0=none 1=ELU 2=sigmoid. K%64==0.
// ---------------------------------------------------------------------------
#define BM 128
#define BN 128
#define BK 64

__global__ __launch_bounds__(256)
void gemm_mfma(const u16* __restrict__ A, const u16* __restrict__ Bt,
               const float* __restrict__ bias,
               float* __restrict__ Cf, u16* __restrict__ Cp,
               int M, int N, int K, int act)
{
    __shared__ __align__(16) u16 sA[BM * BK];   // 16 KB
    __shared__ __align__(16) u16 sB[BN * BK];   // 16 KB
    const int t = threadIdx.x;
    const int w = t >> 6, lane = t & 63;
    const int lr = lane & 15, lg = lane >> 4;

    // bijective XCD-chunk swizzle (8 XCDs)
    const int nwg = gridDim.x * gridDim.y;
    int orig = blockIdx.y * gridDim.x + blockIdx.x;
    int q = nwg >> 3, r = nwg & 7;
    int xcd = orig & 7, slotid = orig >> 3;
    int wgid = (xcd < r ? xcd * (q + 1) : r * (q + 1) + (xcd - r) * q) + slotid;
    int bx = wgid % gridDim.x;
    int by = wgid / gridDim.x;

    const int row0 = by * BM, col0 = bx * BN;
    const int wr = (w & 1) * 64, wc = (w >> 1) * 64;
    const int srow = lane >> 3, slot = lane & 7;   // staging coords in 1KB chunk

    f32x4 acc[4][4];
    #pragma unroll
    for (int m = 0; m < 4; ++m)
        #pragma unroll
        for (int n = 0; n < 4; ++n) acc[m][n] = (f32x4)0.f;

    for (int k0 = 0; k0 < K; k0 += BK) {
        // stage A: 16 chunks of 1KB (8 rows x 128B); wave w takes chunks w*4+i.
        // LDS slot (row, s) receives global k-chunk (s ^ (row&7)).
        #pragma unroll
        for (int i = 0; i < 4; ++i) {
            int ci = w * 4 + i;
            int row = ci * 8 + srow;
            const u16* g = A + (size_t)(row0 + row) * K + k0 + ((slot ^ (row & 7)) << 3);
            gload16(g, &sA[ci * 512]);
        }
        // stage B: 16 chunks (8 cols each)
        #pragma unroll
        for (int i = 0; i < 4; ++i) {
            int ci = w * 4 + i;
            int col = ci * 8 + srow;
            const u16* g = Bt + (size_t)(col0 + col) * K + k0 + ((slot ^ (col & 7)) << 3);
            gload16(g, &sB[ci * 512]);
        }
        __syncthreads();   // drains vmcnt (gload_lds) for all waves
        #pragma unroll
        for (int kk = 0; kk < 2; ++kk) {
            short8 af[4], bfr[4];
            #pragma unroll
            for (int m = 0; m < 4; ++m) {
                int row = wr + m * 16 + lr;
                af[m] = *(const short8*)&sA[row * 64 + (((kk * 4 + lg) ^ (lr & 7)) << 3)];
            }
            #pragma unroll
            for (int n = 0; n < 4; ++n) {
                int col = wc + n * 16 + lr;
                bfr[n] = *(const short8*)&sB[col * 64 + (((kk * 4 + lg) ^ (lr & 7)) << 3)];
            }
            #pragma unroll
            for (int m = 0; m < 4; ++m)
                #pragma unroll
                for (int n = 0; n < 4; ++n)
                    acc[m][n] = __builtin_amdgcn_mfma_f32_16x16x32_bf16(af[m], bfr[n], acc[m][n], 0, 0, 0);
        }
        __syncthreads();
    }

    // epilogue: C/D frag col=lane&15, row=(lane>>4)*4+reg
    #pragma unroll
    for (int m = 0; m < 4; ++m) {
        int grow = row0 + wr + m * 16 + lg * 4;
        #pragma unroll
        for (int n = 0; n < 4; ++n) {
            int gcol = col0 + wc + n * 16 + lr;
            if (gcol >= N) continue;
            float bv = bias ? bias[gcol] : 0.f;
            #pragma unroll
            for (int q2 = 0; q2 < 4; ++q2) {
                int rr = grow + q2;
                if (rr >= M) continue;
                float v = acc[m][n][q2] + bv;
                if (act == 1)      v = fast_elu(v);
                else if (act == 2) v = fast_sigmoid(v);
                size_t o = (size_t)rr * N + gcol;
                if (Cf) Cf[o] = v;
                else Cp[o] = bf16rne(v);
            }
        }
    }
}

// ---------------------------------------------------------------------------
// weight prep (fp32 [K,N] -> transposed bf16 [N,K])
// ---------------------------------------------------------------------------
__global__ __launch_bounds__(256)
void wsplit_conv(const float* __restrict__ Wl1, const float* __restrict__ Wr1,
                 const float* __restrict__ Wl2, const float* __restrict__ Wr2,
                 u16* __restrict__ T1, u16* __restrict__ T2)
{
    int idx = blockIdx.x * 256 + threadIdx.x;   // 0..16383
    int z = blockIdx.y;                          // 0..3
    int k = idx >> 7, n = idx & 127;
    const float* W = (z == 0) ? Wl1 : (z == 1) ? Wr1 : (z == 2) ? Wl2 : Wr2;
    u16* T = (z < 2) ? T1 : T2;
    int half = z & 1;
    T[(size_t)(n + half * 128) * 128 + k] = bf16rne(W[(size_t)k * 128 + n]);
}

// all three MLP weights in one dispatch (flattened element index)
__global__ __launch_bounds__(256)
void wsplit_mlp(const float* __restrict__ W1, const float* __restrict__ W2,
                const float* __restrict__ W3,
                u16* __restrict__ T1, u16* __restrict__ T2, u16* __restrict__ T3)
{
    int i = blockIdx.x * 256 + threadIdx.x;
    const int n1 = 128 * 640, n2 = 640 * 320, n3 = 320 * 64;
    if (i < n1) {
        int k = i / 640, n = i % 640;
        T1[(size_t)n * 128 + k] = bf16rne(W1[i]);
    } else if (i < n1 + n2) {
        int j = i - n1;
        int k = j / 320, n = j % 320;
        T2[(size_t)n * 640 + k] = bf16rne(W2[j]);
    } else if (i < n1 + n2 + n3) {
        int j = i - n1 - n2;
        int k = j / 64, n = j % 64;
        T3[(size_t)n * 320 + k] = bf16rne(W3[j]);
    }
}

__global__ __launch_bounds__(256)
void xsplit_kernel(const float* __restrict__ x, u16* __restrict__ xh, int total)
{
    int i = blockIdx.x * 256 + threadIdx.x;
    if (i >= total) return;
    xh[i] = bf16rne(x[i]);
}

// ---------------------------------------------------------------------------
// CSR build
// ---------------------------------------------------------------------------
__global__ __launch_bounds__(256)
void histo_kernel(const int* __restrict__ ei, int E, int Etot, int* __restrict__ deg)
{
    int e = blockIdx.x * 256 + threadIdx.x;
    if (e >= Etot) return;
    int dst = (e < E) ? ei[E + e] : (e - E);
    atomicAdd(&deg[dst], 1);
}

__global__ __launch_bounds__(256)
void scan1_kernel(const int* __restrict__ deg, int* __restrict__ off,
                  int* __restrict__ bsum, int N)
{
    __shared__ int sh[256];
    int base = blockIdx.x * 1024;
    int t = threadIdx.x;
    int v[4]; int s = 0;
    #pragma unroll
    for (int i = 0; i < 4; ++i) {
        int idx = base + t * 4 + i;
        v[i] = (idx < N) ? deg[idx] : 0;
        s += v[i];
    }
    sh[t] = s;
    __syncthreads();
    for (int d = 1; d < 256; d <<= 1) {
        int x = 0;
        if (t >= d) x = sh[t - d];
        __syncthreads();
        if (t >= d) sh[t] += x;
        __syncthreads();
    }
    int excl = (t > 0) ? sh[t - 1] : 0;
    #pragma unroll
    for (int i = 0; i < 4; ++i) {
        int idx = base + t * 4 + i;
        if (idx < N) off[idx] = excl;
        excl += v[i];
    }
    if (t == 255) bsum[blockIdx.x] = sh[255];
}

__global__ void scan2_kernel(int* __restrict__ bsum, int nb, int* __restrict__ off_last)
{
    if (threadIdx.x == 0) {
        int run = 0;
        for (int i = 0; i < nb; ++i) { int v = bsum[i]; bsum[i] = run; run += v; }
        *off_last = run;
    }
}

__global__ __launch_bounds__(256)
void scan3_kernel(int* __restrict__ off, const int* __restrict__ bsum, int N)
{
    int i = blockIdx.x * 256 + threadIdx.x;
    if (i < N) off[i] += bsum[i >> 10];
}

__global__ __launch_bounds__(256)
void scatter_kernel(const int* __restrict__ ei, int E, int Etot,
                    const int* __restrict__ off, int* __restrict__ cnt,
                    int* __restrict__ csrc)
{
    int e = blockIdx.x * 256 + threadIdx.x;
    if (e >= Etot) return;
    int src, dst;
    if (e < E) { src = ei[e]; dst = ei[E + e]; }
    else       { src = dst = e - E; }
    int pos = off[dst] + atomicAdd(&cnt[dst], 1);
    csrc[pos] = src;
}

// ---------------------------------------------------------------------------
// Fused GATv2 edge pass (VALU-bound ~80%; fast-ELU tail).
// ---------------------------------------------------------------------------
__global__ __launch_bounds__(256)
void gat_fused(const u16* __restrict__ xlxr,
               const int* __restrict__ off, const int* __restrict__ csrc,
               const float* __restrict__ att, const float* __restrict__ bias,
               u16* __restrict__ outp, int N)
{
    const int wave = threadIdx.x >> 6;
    const int lane = threadIdx.x & 63;
    const int node = blockIdx.x * 4 + wave;
    if (node >= N) return;
    const int c = lane * 2;

    const float a0 = att[c];
    const float a1 = att[c + 1];
    u32 xrw = *(const u32*)(xlxr + (size_t)node * 256 + 128 + c);
    const float xr0 = bf16f((u16)xrw);
    const float xr1 = bf16f((u16)(xrw >> 16));

    float acc0 = 0.f, acc1 = 0.f, s = 0.f;
    const int beg = off[node];
    const int end = off[node + 1];

    int e = beg;
    for (; e + 4 <= end; e += 4) {
        int s0 = csrc[e], s1 = csrc[e + 1], s2 = csrc[e + 2], s3 = csrc[e + 3];
        u32 wa = *(const u32*)(xlxr + (size_t)s0 * 256 + c);
        u32 wb = *(const u32*)(xlxr + (size_t)s1 * 256 + c);
        u32 wc = *(const u32*)(xlxr + (size_t)s2 * 256 + c);
        u32 wd = *(const u32*)(xlxr + (size_t)s3 * 256 + c);
        float xa0 = bf16f((u16)wa), xa1 = bf16f((u16)(wa >> 16));
        float xb0 = bf16f((u16)wb), xb1 = bf16f((u16)(wb >> 16));
        float xc0 = bf16f((u16)wc), xc1 = bf16f((u16)(wc >> 16));
        float xd0 = bf16f((u16)wd), xd1 = bf16f((u16)(wd >> 16));
        float t0, t1;
        t0 = xa0 + xr0; t0 = t0 > 0.f ? t0 : 0.2f * t0;
        t1 = xa1 + xr1; t1 = t1 > 0.f ? t1 : 0.2f * t1;
        float za = fmaf(t0, a0, t1 * a1);
        t0 = xb0 + xr0; t0 = t0 > 0.f ? t0 : 0.2f * t0;
        t1 = xb1 + xr1; t1 = t1 > 0.f ? t1 : 0.2f * t1;
        float zb = fmaf(t0, a0, t1 * a1);
        t0 = xc0 + xr0; t0 = t0 > 0.f ? t0 : 0.2f * t0;
        t1 = xc1 + xr1; t1 = t1 > 0.f ? t1 : 0.2f * t1;
        float zc = fmaf(t0, a0, t1 * a1);
        t0 = xd0 + xr0; t0 = t0 > 0.f ? t0 : 0.2f * t0;
        t1 = xd1 + xr1; t1 = t1 > 0.f ? t1 : 0.2f * t1;
        float zd = fmaf(t0, a0, t1 * a1);
        #pragma unroll
        for (int m = 1; m < 16; m <<= 1) {
            za += __shfl_xor(za, m, 64);
            zb += __shfl_xor(zb, m, 64);
            zc += __shfl_xor(zc, m, 64);
            zd += __shfl_xor(zd, m, 64);
        }
        float pa = __expf(za), pb = __expf(zb), pc = __expf(zc), pd = __expf(zd);
        s += (pa + pb) + (pc + pd);
        acc0 = fmaf(pa, xa0, fmaf(pb, xb0, fmaf(pc, xc0, fmaf(pd, xd0, acc0))));
        acc1 = fmaf(pa, xa1, fmaf(pb, xb1, fmaf(pc, xc1, fmaf(pd, xd1, acc1))));
    }
    for (; e < end; ++e) {
        int src = csrc[e];
        u32 xw = *(const u32*)(xlxr + (size_t)src * 256 + c);
        float x0 = bf16f((u16)xw);
        float x1 = bf16f((u16)(xw >> 16));
        float z0 = x0 + xr0; z0 = z0 > 0.f ? z0 : 0.2f * z0;
        float z1 = x1 + xr1; z1 = z1 > 0.f ? z1 : 0.2f * z1;
        float z = fmaf(z0, a0, z1 * a1);
        #pragma unroll
        for (int m = 1; m < 16; m <<= 1)
            z += __shfl_xor(z, m, 64);
        float p = __expf(z);
        s += p;
        acc0 = fmaf(p, x0, acc0);
        acc1 = fmaf(p, x1, acc1);
    }

    float inv = 1.f / s;
    float v0 = fast_elu(acc0 * inv + bias[c]);
    float v1 = fast_elu(acc1 * inv + bias[c + 1]);
    *(u32*)(outp + (size_t)node * 128 + c) = (u32)bf16rne(v0) | ((u32)bf16rne(v1) << 16);
}

// ---------------------------------------------------------------------------
extern "C" void kernel_launch(void* const* d_in, const int* in_sizes, int n_in,
                              void* d_out, int out_size, void* d_ws, size_t ws_size,
                              hipStream_t stream)
{
    const float* x    = (const float*)d_in[0];
    const int*   ei   = (const int*)  d_in[1];
    const float* Wl1  = (const float*)d_in[2];
    const float* Wr1  = (const float*)d_in[3];
    const float* att1 = (const float*)d_in[4];
    const float* b1   = (const float*)d_in[5];
    const float* Wl2  = (const float*)d_in[6];
    const float* Wr2  = (const float*)d_in[7];
    const float* att2 = (const float*)d_in[8];
    const float* b2   = (const float*)d_in[9];
    const float* W1   = (const float*)d_in[10];
    const float* bb1  = (const float*)d_in[11];
    const float* W2   = (const float*)d_in[12];
    const float* bb2  = (const float*)d_in[13];
    const float* W3   = (const float*)d_in[14];
    const float* bb3  = (const float*)d_in[15];
    float* out = (float*)d_out;

    const int Nn   = in_sizes[0] / 128;
    const int E    = in_sizes[1] / 2;
    const int Etot = E + Nn;
    const int PAD  = 128;   // A-side row padding for unguarded gload_lds

    char* base = (char*)d_ws;
    size_t woff = 0;
    auto alloc = [&](size_t bytes) -> void* {
        woff = (woff + 255) & ~(size_t)255;
        void* p = base + woff;
        woff += bytes;
        return p;
    };
    u16* xh   = (u16*)alloc((size_t)(Nn + PAD) * 128 * 2);
    u16* xlxr = (u16*)alloc((size_t)Nn * 256 * 2);
    u16* h1   = (u16*)alloc((size_t)(Nn + PAD) * 128 * 2);
    u16* h2   = (u16*)alloc((size_t)(Nn + PAD) * 128 * 2);
    u16* WLR1 = (u16*)alloc((size_t)256 * 128 * 2);
    u16* WLR2 = (u16*)alloc((size_t)256 * 128 * 2);
    u16* W1t  = (u16*)alloc((size_t)640 * 128 * 2);
    u16* W2t  = (u16*)alloc((size_t)384 * 640 * 2);   // N=320 padded to 384
    u16* W3t  = (u16*)alloc((size_t)128 * 320 * 2);   // N=64 padded to 128
    int* off  = (int*)alloc((size_t)(Nn + 1) * 4);
    int* bsum = (int*)alloc(64 * 4);
    int* deg  = (int*)alloc((size_t)Nn * 4);
    int* csrc = (int*)alloc((size_t)Etot * 4);

    dim3 blk(256);
    auto gemm = [&](const u16* A, const u16* Bt, const float* bias,
                    float* Cf, u16* Cp, int M, int N, int K, int act) {
        dim3 grid((N + BN - 1) / BN, (M + BM - 1) / BM);
        hipLaunchKernelGGL(gemm_mfma, grid, blk, 0, stream, A, Bt, bias, Cf, Cp, M, N, K, act);
    };

    const int eb  = (Etot + 255) / 256;
    const int nb  = (Nn + 1023) / 1024;
    const int nb2 = (Nn + 255) / 256;
    const int gatb = (Nn + 3) / 4;

    // ---- CSR build (once) ----
    hipMemsetAsync(deg, 0, (size_t)Nn * sizeof(int), stream);
    hipLaunchKernelGGL(histo_kernel, dim3(eb), blk, 0, stream, ei, E, Etot, deg);
    hipLaunchKernelGGL(scan1_kernel, dim3(nb), blk, 0, stream, deg, off, bsum, Nn);
    hipLaunchKernelGGL(scan2_kernel, dim3(1), dim3(64), 0, stream, bsum, nb, off + Nn);
    hipLaunchKernelGGL(scan3_kernel, dim3(nb2), blk, 0, stream, off, bsum, Nn);
    hipMemsetAsync(deg, 0, (size_t)Nn * sizeof(int), stream);
    hipLaunchKernelGGL(scatter_kernel, dim3(eb), blk, 0, stream, ei, E, Etot, off, deg, csrc);

    // ---- prep: bf16 convert + transposed weights ----
    hipLaunchKernelGGL(xsplit_kernel, dim3((Nn * 128 + 255) / 256), blk, 0, stream, x, xh, Nn * 128);
    hipLaunchKernelGGL(wsplit_conv, dim3(64, 4), blk, 0, stream, Wl1, Wr1, Wl2, Wr2, WLR1, WLR2);
    const int wtot = 128 * 640 + 640 * 320 + 320 * 64;
    hipLaunchKernelGGL(wsplit_mlp, dim3((wtot + 255) / 256), blk, 0, stream,
                       W1, W2, W3, W1t, W2t, W3t);

    // ---- conv1 ----
    gemm(xh, WLR1, nullptr, nullptr, xlxr, Nn, 256, 128, 0);
    hipLaunchKernelGGL(gat_fused, dim3(gatb), blk, 0, stream, xlxr, off, csrc, att1, b1, h1, Nn);

    // ---- conv2 ----
    gemm(h1, WLR2, nullptr, nullptr, xlxr, Nn, 256, 128, 0);
    hipLaunchKernelGGL(gat_fused, dim3(gatb), blk, 0, stream, xlxr, off, csrc, att2, b2, h2, Nn);

    // ---- MLP head: full-M if workspace allows, else chunked overlay ----
    size_t need = ((size_t)(Nn + PAD) * 640 + (size_t)(Nn + PAD) * 320) * 2 + 512;
    int CHUNK;
    u16 *t1, *t2;
    if (ws_size - woff >= need) {
        CHUNK = Nn;
        t1 = (u16*)alloc((size_t)(Nn + PAD) * 640 * 2);
        t2 = (u16*)alloc((size_t)(Nn + PAD) * 320 * 2);
    } else {
        CHUNK = 25000;                       // overlay dead front region (51.2 MB)
        t1 = (u16*)base;                     // 25128*640*2 = 32.2 MB
        t2 = t1 + (size_t)(CHUNK + PAD) * 640;   // 16.1 MB, total 48.3 < 51.2
    }
    for (int c0 = 0; c0 < Nn; c0 += CHUNK) {
        int cm = (Nn - c0) < CHUNK ? (Nn - c0) : CHUNK;
        gemm(h2 + (size_t)c0 * 128, W1t, bb1, nullptr, t1, cm, 640, 128, 1);
        gemm(t1, W2t, bb2, nullptr, t2, cm, 320, 640, 1);
        gemm(t2, W3t, bb3, out + (size_t)c0 * 64, nullptr, cm, 64, 320, 2);
    }
}